// Round 1
// baseline (516.094 us; speedup 1.0000x reference)
//
#include <hip/hip_runtime.h>

// SOM vector-quantizer fused kernel for MI355X (gfx950).
// Outputs (flat in d_out): [0] loss scalar, [1 .. 8388608] quantized_st
// in [B,C,D,H,W] layout, [8388609 ..] one-hot encodings [N,256].
//
// N = 262144 voxels, EMB_D = 32, K = 256 (16x16 SOM grid).

#define SOM_K      256
#define EMB_D      32
#define N_VOX      262144
#define SPATIAL    32768          // 32*32*32 per batch
#define OUT_ELEMS  8388608        // 8*32*32768
#define COMMIT_DEN 8388608.0f

// ---------------------------------------------------------------------------
// prep: zero the 3 float accumulators (ws is poisoned to 0xAA before every
// launch) and precompute ||W_k||^2 into ws[4+k] so the hot loop reads it via
// a wave-uniform (scalar) load.
// ---------------------------------------------------------------------------
__global__ __launch_bounds__(256) void som_prep_kernel(
    const float* __restrict__ w, float* __restrict__ ws) {
  int t = threadIdx.x;
  if (t < 4) ws[t] = 0.0f;
  float s = 0.0f;
#pragma unroll
  for (int c = 0; c < EMB_D; ++c) {
    float v = w[t * EMB_D + c];
    s = fmaf(v, v, s);
  }
  ws[4 + t] = s;
}

// ---------------------------------------------------------------------------
// main fused kernel: 1024 blocks x 256 threads, one thread per voxel.
// LDS: padded codebook (33-float rows: breaks the stride-32 bank aliasing
// for the divergent neighbor/quantize gathers), per-row ||W||^2, argmin idx.
// ---------------------------------------------------------------------------
__global__ __launch_bounds__(256) void som_main_kernel(
    const float* __restrict__ x,     // [8,32,32,32,32]
    const float* __restrict__ w,     // [256,32]
    const float* __restrict__ wsq,   // [256] = ||W_k||^2  (ws+4)
    float* __restrict__ accum,       // ws[0]=commit ws[1]=som ws[2]=count
    float* __restrict__ out,         // d_out+1, [8,32,32768]
    float* __restrict__ enc) {       // d_out+1+OUT_ELEMS, [N,256]
  __shared__ float wl[SOM_K * 33];   // padded codebook
  __shared__ float wsql[SOM_K];      // ||W_k||^2 for divergent gathers
  __shared__ int   idxs[256];        // per-thread BMU index

  const int t = threadIdx.x;

  // Stage W -> LDS (coalesced read, padded scatter write).
#pragma unroll
  for (int i = 0; i < 32; ++i) {
    int e = i * 256 + t;             // 0..8191
    int r = e >> 5, c = e & 31;
    wl[r * 33 + c] = w[e];
  }
  __syncthreads();

  // Per-row ||W||^2 in LDS (for the divergent neighbor path).
  {
    float s = 0.0f;
#pragma unroll
    for (int c = 0; c < EMB_D; ++c) {
      float v = wl[t * 33 + c];
      s = fmaf(v, v, s);
    }
    wsql[t] = s;
  }

  // Load this voxel's 32-dim vector (coalesced per channel: consecutive
  // threads -> consecutive spatial addresses).
  const int n    = blockIdx.x * 256 + t;
  const int base = (n >> 15) * (EMB_D * SPATIAL) + (n & (SPATIAL - 1));
  float xv[EMB_D];
#pragma unroll
  for (int c = 0; c < EMB_D; ++c) xv[c] = x[base + c * SPATIAL];

  float xsq = 0.0f;
#pragma unroll
  for (int c = 0; c < EMB_D; ++c) xsq = fmaf(xv[c], xv[c], xsq);

  // Distance scan over all 256 codebook rows. k and c are wave-uniform, so
  // w[k*32+c] / wsq[k] should promote to s_load_* (scalar broadcast), keeping
  // this a pure-VALU fmac loop. Strict '<' keeps the FIRST min (np.argmin).
  float best = 3.402823466e38f;
  int   bidx = 0;
  for (int k = 0; k < SOM_K; ++k) {
    float dot = 0.0f;
#pragma unroll
    for (int c = 0; c < EMB_D; ++c) dot = fmaf(w[k * EMB_D + c], xv[c], dot);
    float d = (xsq + wsq[k]) - 2.0f * dot;   // same rounding order as ref
    if (d < best) { best = d; bidx = k; }
  }

  idxs[t] = bidx;
  __syncthreads();   // wl, wsql, idxs all visible from here

  // Quantized output + commitment-loss partial (gather row bidx from LDS).
  float commit = 0.0f;
  {
    const int wb = bidx * 33;
#pragma unroll
    for (int c = 0; c < EMB_D; ++c) {
      float q = wl[wb + c];
      out[base + c * SPATIAL] = q;           // coalesced dword store
      float df = q - xv[c];
      commit = fmaf(df, df, commit);
    }
  }

  // SOM loss: dist to BMU + its up/down/left/right grid neighbors.
  float som = best;
  float cnt = 1.0f;
  {
    const int h  = bidx >> 4;
    const int wc = bidx & 15;
    const int   cand[4]  = { bidx - 16, bidx + 16, bidx - 1, bidx + 1 };
    const float valid[4] = { h > 0 ? 1.f : 0.f,  h < 15 ? 1.f : 0.f,
                             wc > 0 ? 1.f : 0.f, wc < 15 ? 1.f : 0.f };
#pragma unroll
    for (int j = 0; j < 4; ++j) {
      int nk = valid[j] != 0.0f ? cand[j] : bidx;   // clamp (masked anyway)
      float dot = 0.0f;
      const int nb = nk * 33;
#pragma unroll
      for (int c = 0; c < EMB_D; ++c) dot = fmaf(wl[nb + c], xv[c], dot);
      float d = (xsq + wsql[nk]) - 2.0f * dot;
      som = fmaf(valid[j], d, som);
      cnt += valid[j];
    }
  }

  // One-hot encodings, wave-cooperative fully-coalesced dword stores.
  // (The encodings region starts at float offset 8388609 == 4 mod 16, so
  // float4 stores would be misaligned -> use dword passes.)
  {
    const int wave = t >> 6, lane = t & 63;
    const int tileBase = (blockIdx.x * 256 + wave * 64) * SOM_K; // 64 rows
    const int wrow = wave * 64;
    for (int j = 0; j < 256; ++j) {
      int row = j >> 2;                    // wave-uniform
      int col = ((j & 3) << 6) + lane;     // 0..255
      int src = idxs[wrow + row];          // LDS broadcast read
      enc[tileBase + row * SOM_K + col] = (col == src) ? 1.0f : 0.0f;
    }
  }

  // Wave reduction -> 3 atomics per wave (4096 waves, 3 addresses: cheap).
  for (int off = 32; off > 0; off >>= 1) {
    commit += __shfl_down(commit, off, 64);
    som    += __shfl_down(som,    off, 64);
    cnt    += __shfl_down(cnt,    off, 64);
  }
  if ((t & 63) == 0) {
    atomicAdd(accum + 0, commit);
    atomicAdd(accum + 1, som);
    atomicAdd(accum + 2, cnt);
  }
}

// ---------------------------------------------------------------------------
// final: loss = ALPHA * mean(commit) + BETA * som_sum / total_neighbors
// ---------------------------------------------------------------------------
__global__ void som_final_kernel(const float* __restrict__ accum,
                                 float* __restrict__ loss) {
  loss[0] = 6.0f * (accum[0] / COMMIT_DEN) + accum[1] / accum[2];
}

extern "C" void kernel_launch(void* const* d_in, const int* in_sizes, int n_in,
                              void* d_out, int out_size, void* d_ws, size_t ws_size,
                              hipStream_t stream) {
  const float* x = (const float*)d_in[0];   // [8,32,32,32,32]
  const float* w = (const float*)d_in[1];   // [256,32]
  float* ws  = (float*)d_ws;                // [0..3] accums, [4..259] wsq
  float* o   = (float*)d_out;               // [0] loss, then out, then enc

  som_prep_kernel<<<1, 256, 0, stream>>>(w, ws);
  som_main_kernel<<<N_VOX / 256, 256, 0, stream>>>(
      x, w, ws + 4, ws, o + 1, o + 1 + OUT_ELEMS);
  som_final_kernel<<<1, 1, 0, stream>>>(ws, o);
}

// Round 2
// 488.403 us; speedup vs baseline: 1.0567x; 1.0567x over previous
//
#include <hip/hip_runtime.h>

// SOM vector-quantizer fused kernel for MI355X (gfx950).
// Outputs (flat in d_out): [0] loss scalar, [1 .. 8388608] quantized_st
// in [B,C,D,H,W] layout, [8388609 ..] one-hot encodings [N,256].
//
// N = 262144 voxels, EMB_D = 32, K = 256 (16x16 SOM grid).
//
// R1 -> R2: encodings write restructured. R1 did 256 dependent
// ds_read(idxs)+store iterations per thread (latency-bound, ~180us).
// Now each wave broadcasts its own 64 BMU indices via v_readlane
// (register-only) and issues pure streaming stores.

#define SOM_K      256
#define EMB_D      32
#define N_VOX      262144
#define SPATIAL    32768          // 32*32*32 per batch
#define OUT_ELEMS  8388608        // 8*32*32768
#define COMMIT_DEN 8388608.0f

// ---------------------------------------------------------------------------
// prep: zero the 3 float accumulators (ws is poisoned to 0xAA before every
// launch) and precompute ||W_k||^2 into ws[4+k] so the hot loop reads it via
// a wave-uniform (scalar) load.
// ---------------------------------------------------------------------------
__global__ __launch_bounds__(256) void som_prep_kernel(
    const float* __restrict__ w, float* __restrict__ ws) {
  int t = threadIdx.x;
  if (t < 4) ws[t] = 0.0f;
  float s = 0.0f;
#pragma unroll
  for (int c = 0; c < EMB_D; ++c) {
    float v = w[t * EMB_D + c];
    s = fmaf(v, v, s);
  }
  ws[4 + t] = s;
}

// ---------------------------------------------------------------------------
// main fused kernel: 1024 blocks x 256 threads, one thread per voxel.
// LDS: padded codebook (33-float rows: breaks the stride-32 bank aliasing
// for the divergent neighbor/quantize gathers) + per-row ||W||^2.
// ---------------------------------------------------------------------------
__global__ __launch_bounds__(256) void som_main_kernel(
    const float* __restrict__ x,     // [8,32,32,32,32]
    const float* __restrict__ w,     // [256,32]
    const float* __restrict__ wsq,   // [256] = ||W_k||^2  (ws+4)
    float* __restrict__ accum,       // ws[0]=commit ws[1]=som ws[2]=count
    float* __restrict__ out,         // d_out+1, [8,32,32768]
    float* __restrict__ enc) {       // d_out+1+OUT_ELEMS, [N,256]
  __shared__ float wl[SOM_K * 33];   // padded codebook
  __shared__ float wsql[SOM_K];      // ||W_k||^2 for divergent gathers

  const int t = threadIdx.x;

  // Stage W -> LDS (coalesced read, padded scatter write).
#pragma unroll
  for (int i = 0; i < 32; ++i) {
    int e = i * 256 + t;             // 0..8191
    int r = e >> 5, c = e & 31;
    wl[r * 33 + c] = w[e];
  }

  // Per-row ||W||^2 into LDS (for the divergent neighbor path).
  {
    float s = 0.0f;
#pragma unroll
    for (int c = 0; c < EMB_D; ++c) {
      float v = w[t * EMB_D + c];
      s = fmaf(v, v, s);
    }
    wsql[t] = s;
  }

  // Load this voxel's 32-dim vector (coalesced per channel: consecutive
  // threads -> consecutive spatial addresses).
  const int n    = blockIdx.x * 256 + t;
  const int base = (n >> 15) * (EMB_D * SPATIAL) + (n & (SPATIAL - 1));
  float xv[EMB_D];
#pragma unroll
  for (int c = 0; c < EMB_D; ++c) xv[c] = x[base + c * SPATIAL];

  float xsq = 0.0f;
#pragma unroll
  for (int c = 0; c < EMB_D; ++c) xsq = fmaf(xv[c], xv[c], xsq);

  // Distance scan over all 256 codebook rows. k and c are wave-uniform, so
  // w[k*32+c] / wsq[k] promote to s_load_* (scalar broadcast), keeping this
  // a pure-VALU fmac loop. Strict '<' keeps the FIRST min (np.argmin).
  // NOTE: keep this exact accumulation order — R1 matched the reference
  // argmin everywhere (absmax 0.0).
  float best = 3.402823466e38f;
  int   bidx = 0;
  for (int k = 0; k < SOM_K; ++k) {
    float dot = 0.0f;
#pragma unroll
    for (int c = 0; c < EMB_D; ++c) dot = fmaf(w[k * EMB_D + c], xv[c], dot);
    float d = (xsq + wsq[k]) - 2.0f * dot;   // same rounding order as ref
    if (d < best) { best = d; bidx = k; }
  }

  __syncthreads();   // wl, wsql visible from here

  // One-hot encodings: each wave owns its 64 voxels' rows. The BMU index of
  // row r is lane r's bidx -> broadcast with v_readlane (no LDS, no loads).
  // Stores are fire-and-forget, fully coalesced 256B/wave dword stores (the
  // enc region starts at float offset 8388609 == 4 mod 16, so dword it is).
  {
    const int lane = t & 63, wave = t >> 6;
    float* ep = enc + (size_t)(blockIdx.x * 256 + wave * 64) * SOM_K + lane;
    const int c1 = lane + 64, c2 = lane + 128, c3 = lane + 192;
    for (int row = 0; row < 64; ++row) {
      const int src = __builtin_amdgcn_readlane(bidx, row);  // wave-uniform
      ep[0]   = (lane == src) ? 1.0f : 0.0f;
      ep[64]  = (c1   == src) ? 1.0f : 0.0f;
      ep[128] = (c2   == src) ? 1.0f : 0.0f;
      ep[192] = (c3   == src) ? 1.0f : 0.0f;
      ep += SOM_K;
    }
  }

  // Quantized output + commitment-loss partial (gather row bidx from LDS).
  float commit = 0.0f;
  {
    const int wb = bidx * 33;
#pragma unroll
    for (int c = 0; c < EMB_D; ++c) {
      float q = wl[wb + c];
      out[base + c * SPATIAL] = q;           // coalesced dword store
      float df = q - xv[c];
      commit = fmaf(df, df, commit);
    }
  }

  // SOM loss: dist to BMU + its up/down/left/right grid neighbors.
  float som = best;
  float cnt = 1.0f;
  {
    const int h  = bidx >> 4;
    const int wc = bidx & 15;
    const int   cand[4]  = { bidx - 16, bidx + 16, bidx - 1, bidx + 1 };
    const float valid[4] = { h > 0 ? 1.f : 0.f,  h < 15 ? 1.f : 0.f,
                             wc > 0 ? 1.f : 0.f, wc < 15 ? 1.f : 0.f };
#pragma unroll
    for (int j = 0; j < 4; ++j) {
      int nk = valid[j] != 0.0f ? cand[j] : bidx;   // clamp (masked anyway)
      float dot = 0.0f;
      const int nb = nk * 33;
#pragma unroll
      for (int c = 0; c < EMB_D; ++c) dot = fmaf(wl[nb + c], xv[c], dot);
      float d = (xsq + wsql[nk]) - 2.0f * dot;
      som = fmaf(valid[j], d, som);
      cnt += valid[j];
    }
  }

  // Wave reduction -> 3 atomics per wave (4096 waves, 3 addresses: cheap).
  for (int off = 32; off > 0; off >>= 1) {
    commit += __shfl_down(commit, off, 64);
    som    += __shfl_down(som,    off, 64);
    cnt    += __shfl_down(cnt,    off, 64);
  }
  if ((t & 63) == 0) {
    atomicAdd(accum + 0, commit);
    atomicAdd(accum + 1, som);
    atomicAdd(accum + 2, cnt);
  }
}

// ---------------------------------------------------------------------------
// final: loss = ALPHA * mean(commit) + BETA * som_sum / total_neighbors
// ---------------------------------------------------------------------------
__global__ void som_final_kernel(const float* __restrict__ accum,
                                 float* __restrict__ loss) {
  loss[0] = 6.0f * (accum[0] / COMMIT_DEN) + accum[1] / accum[2];
}

extern "C" void kernel_launch(void* const* d_in, const int* in_sizes, int n_in,
                              void* d_out, int out_size, void* d_ws, size_t ws_size,
                              hipStream_t stream) {
  const float* x = (const float*)d_in[0];   // [8,32,32,32,32]
  const float* w = (const float*)d_in[1];   // [256,32]
  float* ws  = (float*)d_ws;                // [0..3] accums, [4..259] wsq
  float* o   = (float*)d_out;               // [0] loss, then out, then enc

  som_prep_kernel<<<1, 256, 0, stream>>>(w, ws);
  som_main_kernel<<<N_VOX / 256, 256, 0, stream>>>(
      x, w, ws + 4, ws, o + 1, o + 1 + OUT_ELEMS);
  som_final_kernel<<<1, 1, 0, stream>>>(ws, o);
}

// Round 3
// 413.157 us; speedup vs baseline: 1.2491x; 1.1821x over previous
//
#include <hip/hip_runtime.h>

// SOM vector-quantizer fused kernel for MI355X (gfx950).
// Outputs (flat in d_out): [0] loss scalar, [1 .. 8388608] quantized_st
// in [B,C,D,H,W] layout, [8388609 ..] one-hot encodings [N,256].
//
// N = 262144 voxels, EMB_D = 32, K = 256 (16x16 SOM grid).
//
// R2 -> R3:
//  * distance scan reads W via LDS same-address float4 broadcast
//    (ds_read_b128, rows padded to 36 floats for 16B alignment) instead of
//    relying on s_load promotion of global reads — deterministic operand
//    delivery, no possible per-lane VMEM flood.
//  * per-wave loss atomics spread over 256 cache-line-spaced slots
//    (was 3 shared addresses -> full serialization at one L2 point).
//  * enc one-hot stores issued immediately after the scan so the 268 MB
//    write stream drains under the LDS gather phases.

#define SOM_K      256
#define EMB_D      32
#define WPAD       36             // LDS row stride (floats): 16B-aligned rows
#define N_VOX      262144
#define SPATIAL    32768          // 32*32*32 per batch
#define OUT_ELEMS  8388608        // 8*32*32768
#define COMMIT_DEN 8388608.0f
#define NSLOT      256            // loss accumulator slots (64B apart)

// ---------------------------------------------------------------------------
// prep: zero the slot accumulators (ws is poisoned to 0xAA every launch).
// Layout: ws[slot*16 + {0,1,2}] = {commit, som, count} partials.
// ---------------------------------------------------------------------------
__global__ __launch_bounds__(256) void som_prep_kernel(float* __restrict__ ws) {
  float4* p = (float4*)ws;               // 256 slots * 16 floats = 1024 float4
  int t = threadIdx.x;
#pragma unroll
  for (int i = 0; i < 4; ++i) p[i * 256 + t] = make_float4(0.f, 0.f, 0.f, 0.f);
}

// ---------------------------------------------------------------------------
// main fused kernel: 1024 blocks x 256 threads, one thread per voxel.
// LDS: codebook padded to 36-float rows (16B-aligned for b128 broadcast;
// stride 36 -> 8-way worst-case conflict on divergent gathers, fine for the
// short gather phases) + per-row ||W||^2.
// ---------------------------------------------------------------------------
__global__ __launch_bounds__(256) void som_main_kernel(
    const float* __restrict__ x,     // [8,32,32,32,32]
    const float* __restrict__ w,     // [256,32]
    float* __restrict__ slots,       // ws: NSLOT x 16 floats
    float* __restrict__ out,         // d_out+1, [8,32,32768]
    float* __restrict__ enc) {       // d_out+1+OUT_ELEMS, [N,256]
  __shared__ __align__(16) float wl[SOM_K * WPAD];
  __shared__ float wsql[SOM_K];      // ||W_k||^2

  const int t = threadIdx.x;

  // Issue the voxel loads FIRST so they overlap the LDS staging below.
  const int n    = blockIdx.x * 256 + t;
  const int base = (n >> 15) * (EMB_D * SPATIAL) + (n & (SPATIAL - 1));
  float xv[EMB_D];
#pragma unroll
  for (int c = 0; c < EMB_D; ++c) xv[c] = x[base + c * SPATIAL];

  // Stage W -> LDS (coalesced read, padded scatter write).
#pragma unroll
  for (int i = 0; i < 32; ++i) {
    int e = i * 256 + t;             // 0..8191
    int r = e >> 5, c = e & 31;
    wl[r * WPAD + c] = w[e];
  }
  // ||W_t||^2, same sequential-fmaf order as the reference-matched R1/R2.
  {
    float s = 0.0f;
#pragma unroll
    for (int c = 0; c < EMB_D; ++c) {
      float v = w[t * EMB_D + c];
      s = fmaf(v, v, s);
    }
    wsql[t] = s;
  }
  __syncthreads();

  float xsq = 0.0f;
#pragma unroll
  for (int c = 0; c < EMB_D; ++c) xsq = fmaf(xv[c], xv[c], xsq);

  // Distance scan over all 256 codebook rows. All 64 lanes read the SAME
  // LDS address -> broadcast, conflict-free, ds_read_b128 (rows 16B-aligned).
  // Keep the exact sequential fmaf order (R1/R2: absmax 0.0).
  float best = 3.402823466e38f;
  int   bidx = 0;
#pragma unroll 2
  for (int k = 0; k < SOM_K; ++k) {
    const float4* row = (const float4*)(wl + k * WPAD);
    float dot = 0.0f;
#pragma unroll
    for (int j = 0; j < 8; ++j) {
      float4 q = row[j];
      dot = fmaf(q.x, xv[4 * j + 0], dot);
      dot = fmaf(q.y, xv[4 * j + 1], dot);
      dot = fmaf(q.z, xv[4 * j + 2], dot);
      dot = fmaf(q.w, xv[4 * j + 3], dot);
    }
    float d = (xsq + wsql[k]) - 2.0f * dot;   // same rounding order as ref
    if (d < best) { best = d; bidx = k; }
  }

  // One-hot encodings FIRST (only needs bidx): start draining the 268 MB
  // write stream while the LDS gather phases below run. Each wave broadcasts
  // its own 64 BMU indices via v_readlane; stores are coalesced 256B dwords
  // (enc region starts at float offset 8388609 == 1 mod 4 -> dword only).
  {
    const int lane = t & 63, wave = t >> 6;
    float* ep = enc + (size_t)(blockIdx.x * 256 + wave * 64) * SOM_K + lane;
    const int c1 = lane + 64, c2 = lane + 128, c3 = lane + 192;
    for (int row = 0; row < 64; ++row) {
      const int src = __builtin_amdgcn_readlane(bidx, row);  // wave-uniform
      ep[0]   = (lane == src) ? 1.0f : 0.0f;
      ep[64]  = (c1   == src) ? 1.0f : 0.0f;
      ep[128] = (c2   == src) ? 1.0f : 0.0f;
      ep[192] = (c3   == src) ? 1.0f : 0.0f;
      ep += SOM_K;
    }
  }

  // Quantized output + commitment-loss partial (gather row bidx from LDS).
  float commit = 0.0f;
  {
    const float4* qrow = (const float4*)(wl + bidx * WPAD);
#pragma unroll
    for (int j = 0; j < 8; ++j) {
      float4 q = qrow[j];
      float qq[4] = { q.x, q.y, q.z, q.w };
#pragma unroll
      for (int u = 0; u < 4; ++u) {
        int c = 4 * j + u;
        out[base + c * SPATIAL] = qq[u];     // coalesced dword store
        float df = qq[u] - xv[c];
        commit = fmaf(df, df, commit);
      }
    }
  }

  // SOM loss: dist to BMU + its up/down/left/right grid neighbors.
  float som = best;
  float cnt = 1.0f;
  {
    const int h  = bidx >> 4;
    const int wc = bidx & 15;
    const int   cand[4]  = { bidx - 16, bidx + 16, bidx - 1, bidx + 1 };
    const float valid[4] = { h > 0 ? 1.f : 0.f,  h < 15 ? 1.f : 0.f,
                             wc > 0 ? 1.f : 0.f, wc < 15 ? 1.f : 0.f };
#pragma unroll
    for (int j = 0; j < 4; ++j) {
      int nk = valid[j] != 0.0f ? cand[j] : bidx;   // clamp (masked anyway)
      const float4* nrow = (const float4*)(wl + nk * WPAD);
      float dot = 0.0f;
#pragma unroll
      for (int jj = 0; jj < 8; ++jj) {
        float4 q = nrow[jj];
        dot = fmaf(q.x, xv[4 * jj + 0], dot);
        dot = fmaf(q.y, xv[4 * jj + 1], dot);
        dot = fmaf(q.z, xv[4 * jj + 2], dot);
        dot = fmaf(q.w, xv[4 * jj + 3], dot);
      }
      float d = (xsq + wsql[nk]) - 2.0f * dot;
      som = fmaf(valid[j], d, som);
      cnt += valid[j];
    }
  }

  // Wave reduction -> 3 atomics per wave into this block's slot (slots are
  // 64B apart; 16 waves/slot -> negligible contention, parallel L2 banks).
  for (int off = 32; off > 0; off >>= 1) {
    commit += __shfl_down(commit, off, 64);
    som    += __shfl_down(som,    off, 64);
    cnt    += __shfl_down(cnt,    off, 64);
  }
  if ((t & 63) == 0) {
    float* sp = slots + (size_t)(blockIdx.x & (NSLOT - 1)) * 16;
    atomicAdd(sp + 0, commit);
    atomicAdd(sp + 1, som);
    atomicAdd(sp + 2, cnt);
  }
}

// ---------------------------------------------------------------------------
// final: reduce the 256 slots with one wave, then
// loss = ALPHA * mean(commit) + BETA * som_sum / total_neighbors
// ---------------------------------------------------------------------------
__global__ __launch_bounds__(64) void som_final_kernel(
    const float* __restrict__ slots, float* __restrict__ loss) {
  const int t = threadIdx.x;           // one wave
  float commit = 0.f, som = 0.f, cnt = 0.f;
#pragma unroll
  for (int i = 0; i < 4; ++i) {
    const float* sp = slots + (size_t)(i * 64 + t) * 16;
    commit += sp[0]; som += sp[1]; cnt += sp[2];
  }
  for (int off = 32; off > 0; off >>= 1) {
    commit += __shfl_down(commit, off, 64);
    som    += __shfl_down(som,    off, 64);
    cnt    += __shfl_down(cnt,    off, 64);
  }
  if (t == 0) loss[0] = 6.0f * (commit / COMMIT_DEN) + som / cnt;
}

extern "C" void kernel_launch(void* const* d_in, const int* in_sizes, int n_in,
                              void* d_out, int out_size, void* d_ws, size_t ws_size,
                              hipStream_t stream) {
  const float* x = (const float*)d_in[0];   // [8,32,32,32,32]
  const float* w = (const float*)d_in[1];   // [256,32]
  float* ws  = (float*)d_ws;                // NSLOT x 16 float slots
  float* o   = (float*)d_out;               // [0] loss, then out, then enc

  som_prep_kernel<<<1, 256, 0, stream>>>(ws);
  som_main_kernel<<<N_VOX / 256, 256, 0, stream>>>(
      x, w, ws, o + 1, o + 1 + OUT_ELEMS);
  som_final_kernel<<<1, 64, 0, stream>>>(ws, o);
}